// Round 2
// baseline (3585.880 us; speedup 1.0000x reference)
//
#include <hip/hip_runtime.h>
#include <hip/hip_bf16.h>
#include <math.h>

#define B_ 2
#define T_ 2048
#define C_ 1024
#define H_ 16
#define D_ 64
#define CS_ 64
#define NC_ 32
#define NS_ 5
#define IST 136   // interleaved row stride in shorts (64 elems * 2 + 8 pad; 16B-aligned)

typedef __attribute__((ext_vector_type(8))) short bf16x8;
typedef __attribute__((ext_vector_type(4))) float f32x4;
typedef __attribute__((ext_vector_type(16))) float f32x16;

__device__ inline void split2(float x, unsigned short& h, unsigned short& l) {
    __hip_bfloat16 bh = __float2bfloat16(x);           // hw cvt
    float lo = x - __bfloat162float(bh);
    __hip_bfloat16 bl = __float2bfloat16(lo);
    h = __builtin_bit_cast(unsigned short, bh);
    l = __builtin_bit_cast(unsigned short, bl);
}

// ---------------------------------------------------------------------------
// split f32 -> (hi, lo) bf16 buffers
// ---------------------------------------------------------------------------
__global__ __launch_bounds__(256) void split_kernel(const float* __restrict__ src,
                                                    unsigned short* __restrict__ hi,
                                                    unsigned short* __restrict__ lo,
                                                    int n) {
    int i = (blockIdx.x * 256 + threadIdx.x) * 4;
    if (i >= n) return;
    float4 v = *(const float4*)&src[i];
    unsigned short h0, l0, h1, l1, h2, l2, h3, l3;
    split2(v.x, h0, l0); split2(v.y, h1, l1);
    split2(v.z, h2, l2); split2(v.w, h3, l3);
    uint2 hv = make_uint2((unsigned)h0 | ((unsigned)h1 << 16), (unsigned)h2 | ((unsigned)h3 << 16));
    uint2 lv = make_uint2((unsigned)l0 | ((unsigned)l1 << 16), (unsigned)l2 | ((unsigned)l3 << 16));
    *(uint2*)&hi[i] = hv;
    *(uint2*)&lo[i] = lv;
}

// ---------------------------------------------------------------------------
// Split-precision bf16 MFMA GEMM (unchanged).
// ---------------------------------------------------------------------------
__global__ __launch_bounds__(256, 1) void gemm_split(const unsigned short* __restrict__ Ah,
                                                     const unsigned short* __restrict__ Al,
                                                     const unsigned short* __restrict__ Bh,
                                                     const unsigned short* __restrict__ Bl,
                                                     float* __restrict__ out) {
    __shared__ __align__(16) unsigned short sAh[128 * 72];
    __shared__ __align__(16) unsigned short sAl[128 * 72];
    __shared__ __align__(16) unsigned short sBh[128 * 72];
    __shared__ __align__(16) unsigned short sBl[128 * 72];
    int tid = threadIdx.x;
    int m0 = blockIdx.y * 128, n0 = blockIdx.x * 128;
    int w = tid >> 6, lane = tid & 63, q = lane >> 4, c = lane & 15;
    int mq = (w >> 1) * 64, nq = (w & 1) * 64;
    f32x4 acc[4][4];
    #pragma unroll
    for (int i = 0; i < 4; i++)
        #pragma unroll
        for (int j = 0; j < 4; j++) acc[i][j] = (f32x4){0.f, 0.f, 0.f, 0.f};
    int lrow = tid >> 2, lseg = (tid & 3) * 16;
    for (int kt = 0; kt < C_; kt += 64) {
        #pragma unroll
        for (int rr = 0; rr < 2; rr++) {
            int row = lrow + rr * 64;
            const size_t ga = (size_t)(m0 + row) * C_ + kt + lseg;
            const size_t gb = (size_t)(n0 + row) * C_ + kt + lseg;
            bf16x8 vah0 = *(const bf16x8*)&Ah[ga];
            bf16x8 vah1 = *(const bf16x8*)&Ah[ga + 8];
            bf16x8 val0 = *(const bf16x8*)&Al[ga];
            bf16x8 val1 = *(const bf16x8*)&Al[ga + 8];
            bf16x8 vbh0 = *(const bf16x8*)&Bh[gb];
            bf16x8 vbh1 = *(const bf16x8*)&Bh[gb + 8];
            bf16x8 vbl0 = *(const bf16x8*)&Bl[gb];
            bf16x8 vbl1 = *(const bf16x8*)&Bl[gb + 8];
            *(bf16x8*)&sAh[row * 72 + lseg] = vah0;
            *(bf16x8*)&sAh[row * 72 + lseg + 8] = vah1;
            *(bf16x8*)&sAl[row * 72 + lseg] = val0;
            *(bf16x8*)&sAl[row * 72 + lseg + 8] = val1;
            *(bf16x8*)&sBh[row * 72 + lseg] = vbh0;
            *(bf16x8*)&sBh[row * 72 + lseg + 8] = vbh1;
            *(bf16x8*)&sBl[row * 72 + lseg] = vbl0;
            *(bf16x8*)&sBl[row * 72 + lseg + 8] = vbl1;
        }
        __syncthreads();
        #pragma unroll
        for (int t = 0; t < 2; t++) {
            bf16x8 af[4][2], bfr[4][2];
            #pragma unroll
            for (int i = 0; i < 4; i++) {
                af[i][0] = *(const bf16x8*)&sAh[(mq + 16 * i + c) * 72 + t * 32 + q * 8];
                af[i][1] = *(const bf16x8*)&sAl[(mq + 16 * i + c) * 72 + t * 32 + q * 8];
            }
            #pragma unroll
            for (int j = 0; j < 4; j++) {
                bfr[j][0] = *(const bf16x8*)&sBh[(nq + 16 * j + c) * 72 + t * 32 + q * 8];
                bfr[j][1] = *(const bf16x8*)&sBl[(nq + 16 * j + c) * 72 + t * 32 + q * 8];
            }
            #pragma unroll
            for (int i = 0; i < 4; i++)
                #pragma unroll
                for (int j = 0; j < 4; j++) {
                    acc[i][j] = __builtin_amdgcn_mfma_f32_16x16x32_bf16(af[i][0], bfr[j][0], acc[i][j], 0, 0, 0);
                    acc[i][j] = __builtin_amdgcn_mfma_f32_16x16x32_bf16(af[i][0], bfr[j][1], acc[i][j], 0, 0, 0);
                    acc[i][j] = __builtin_amdgcn_mfma_f32_16x16x32_bf16(af[i][1], bfr[j][0], acc[i][j], 0, 0, 0);
                }
        }
        __syncthreads();
    }
    #pragma unroll
    for (int i = 0; i < 4; i++)
        #pragma unroll
        for (int j = 0; j < 4; j++)
            #pragma unroll
            for (int r = 0; r < 4; r++)
                out[(size_t)(m0 + mq + 16 * i + 4 * q + r) * C_ + n0 + nq + 16 * j + c] = acc[i][j][r];
}

// ---------------------------------------------------------------------------
// Causal depthwise conv (K=4) + optional per-head RMS norm + optional poly.
// ---------------------------------------------------------------------------
__global__ __launch_bounds__(256) void conv_kernel(const float* __restrict__ xin,
                                                   const float* __restrict__ w,
                                                   const float* __restrict__ bias,
                                                   float* __restrict__ out, int mode) {
    int bt = blockIdx.x;
    int t = bt & (T_ - 1);
    int tid = threadIdx.x;
    int c0 = tid * 4;
    float4 w4[4];
    #pragma unroll
    for (int i = 0; i < 4; i++) w4[i] = *(const float4*)&w[(c0 + i) * 4];
    float4 bi = *(const float4*)&bias[c0];
    float4 xs[4];
    #pragma unroll
    for (int j = 0; j < 4; j++) {
        int tt = t - 3 + j;
        xs[j] = (tt >= 0) ? *(const float4*)&xin[(bt - 3 + j) * C_ + c0]
                          : make_float4(0.f, 0.f, 0.f, 0.f);
    }
    float y0 = bi.x + w4[0].x * xs[0].x + w4[0].y * xs[1].x + w4[0].z * xs[2].x + w4[0].w * xs[3].x;
    float y1 = bi.y + w4[1].x * xs[0].y + w4[1].y * xs[1].y + w4[1].z * xs[2].y + w4[1].w * xs[3].y;
    float y2 = bi.z + w4[2].x * xs[0].z + w4[2].y * xs[1].z + w4[2].z * xs[2].z + w4[2].w * xs[3].z;
    float y3 = bi.w + w4[3].x * xs[0].w + w4[3].y * xs[1].w + w4[3].z * xs[2].w + w4[3].w * xs[3].w;
    if (mode >= 1) {
        float ss = y0 * y0 + y1 * y1 + y2 * y2 + y3 * y3;
        ss += __shfl_xor(ss, 1);
        ss += __shfl_xor(ss, 2);
        ss += __shfl_xor(ss, 4);
        ss += __shfl_xor(ss, 8);
        float sc = rsqrtf(ss * (1.f / 64.f) + 1e-6f);
        y0 *= sc; y1 *= sc; y2 *= sc; y3 *= sc;
        if (mode == 2) {
            y0 += 0.5f * y0 * y0; y1 += 0.5f * y1 * y1;
            y2 += 0.5f * y2 * y2; y3 += 0.5f * y3 * y3;
        }
    }
    *(float4*)&out[bt * C_ + c0] = make_float4(y0, y1, y2, y3);
}

// ---------------------------------------------------------------------------
// Gate projections.
// ---------------------------------------------------------------------------
__global__ __launch_bounds__(256) void gates_kernel(const float* __restrict__ x,
                                                    const float* __restrict__ Wa,
                                                    const float* __restrict__ We,
                                                    const float* __restrict__ Wt,
                                                    const float* __restrict__ Wg,
                                                    float* __restrict__ gates) {
    __shared__ float xs[C_];
    int bt = blockIdx.x, tid = threadIdx.x;
    *(float4*)&xs[tid * 4] = *(const float4*)&x[bt * C_ + tid * 4];
    __syncthreads();
    int dot = tid >> 2, l = tid & 3;
    int g = dot >> 4, h = dot & 15;
    const float* Wp = (g == 0) ? Wa : (g == 1) ? We : (g == 2) ? Wt : Wg;
    const float* Wr = Wp + h * C_;
    float p = 0.f;
    for (int c = l * 4; c < C_; c += 16) {
        float4 wv = *(const float4*)&Wr[c];
        float4 xv = *(const float4*)&xs[c];
        p += wv.x * xv.x + wv.y * xv.y + wv.z * xv.z + wv.w * xv.w;
    }
    p += __shfl_xor(p, 1);
    p += __shfl_xor(p, 2);
    if (l == 0) gates[g * (B_ * T_ * H_) + bt * H_ + h] = 1.f / (1.f + __expf(-p));
}

// ---------------------------------------------------------------------------
// chunk_s: standalone (chunk 0 only) — unchanged.
// ---------------------------------------------------------------------------
__global__ __launch_bounds__(256) void chunk_s_kernel(const float* __restrict__ kbuf,
                                                      const float* __restrict__ vbuf,
                                                      const float* __restrict__ gates,
                                                      const float* __restrict__ Mc,
                                                      float* __restrict__ Sc,
                                                      float* __restrict__ chunkS,
                                                      int chunk) {
    __shared__ float Kc[CS_][68];
    __shared__ float Mrow[8][68];
    __shared__ float errS[CS_][8];
    __shared__ float thS[CS_], etS[CS_], gmS[CS_];
    int tid = threadIdx.x;
    int idx = blockIdx.x;
    int vt = idx & 7, h = (idx >> 3) & 15, b = idx >> 7;
    int c0t = chunk * CS_;
    {
        int row = tid >> 2, col = (tid & 3) * 16;
        const float* src = &kbuf[((size_t)(b * T_ + c0t + row) * H_ + h) * D_];
        #pragma unroll
        for (int i = 0; i < 4; i++)
            *(float4*)&Kc[row][col + i * 4] = *(const float4*)&src[col + i * 4];
    }
    if (tid < 128) {
        int v = tid >> 4, cc = (tid & 15) * 4;
        *(float4*)&Mrow[v][cc] =
            *(const float4*)&Mc[((size_t)(b * H_ + h)) * 4096 + (vt * 8 + v) * 64 + cc];
    }
    if (tid < CS_)           thS[tid] = gates[2 * (B_ * T_ * H_) + (b * T_ + c0t + tid) * H_ + h];
    else if (tid < 2 * CS_)  { int t = tid - CS_;     etS[t] = gates[1 * (B_ * T_ * H_) + (b * T_ + c0t + t) * H_ + h]; }
    else if (tid < 3 * CS_)  { int t = tid - 2 * CS_; gmS[t] = gates[3 * (B_ * T_ * H_) + (b * T_ + c0t + t) * H_ + h]; }
    __syncthreads();
    {
        int t = tid >> 2, v0 = (tid & 3) * 2;
        float s0 = 0.f, s1 = 0.f;
        #pragma unroll
        for (int k = 0; k < 64; k += 4) {
            float4 kv = *(float4*)&Kc[t][k];
            float4 m0 = *(float4*)&Mrow[v0][k];
            float4 m1 = *(float4*)&Mrow[v0 + 1][k];
            s0 += kv.x * m0.x + kv.y * m0.y + kv.z * m0.z + kv.w * m0.w;
            s1 += kv.x * m1.x + kv.y * m1.y + kv.z * m1.z + kv.w * m1.w;
        }
        const float* vp = &vbuf[((size_t)(b * T_ + c0t + t) * H_ + h) * D_ + vt * 8 + v0];
        errS[t][v0]     = s0 - vp[0];
        errS[t][v0 + 1] = s1 - vp[1];
    }
    __syncthreads();
    int vl = tid >> 5;
    int kk = (tid & 31) * 2;
    size_t sIdx = ((size_t)(b * H_ + h)) * 4096 + (vt * 8 + vl) * 64 + kk;
    float S0 = Sc[sIdx], S1 = Sc[sIdx + 1];
    float ring0[16] = {}, ring1[16] = {};
    float cum0 = 0.f, cum1 = 0.f;
    for (int cb = 0; cb < 4; ++cb) {
        #pragma unroll
        for (int ci = 0; ci < 16; ++ci) {
            int c = cb * 16 + ci;
            float er = 2.f * errS[c][vl];
            float2 kv = *(float2*)&Kc[c][kk];
            float g = gmS[c];
            cum0 += g * er * kv.x;
            cum1 += g * er * kv.y;
            float uw0 = cum0 - ring0[ci];
            float uw1 = cum1 - ring1[ci];
            ring0[ci] = cum0; ring1[ci] = cum1;
            float th = thS[c], et = etS[c];
            S0 = th * S0 - et * uw0;
            S1 = th * S1 - et * uw1;
            size_t o = ((size_t)((b * H_ + h) * CS_ + c)) * 4096 + (vt * 8 + vl) * 64 + kk;
            *(float2*)&chunkS[o] = make_float2(S0, S1);
        }
    }
    Sc[sIdx] = S0; Sc[sIdx + 1] = S1;
}

// ---------------------------------------------------------------------------
// Polar-Express, interleaved-split bf16, 32x32x16 MFMA, QUADRANT ownership:
// wave w owns the 32x32 output quadrant (R=w>>1, C=w&1) of every matmul —
// exactly ONE 32x32 MFMA tile (f32x16 acc). Split-product via interleaved
// hi/lo shorts: mfma(a,b) gives hh+ll, mfma(swap16(a),b) gives hl+lh.
// A-frag: row=lane&31, k-half=lane>>5. C/D: col=lane&31,
// row=(reg&3)+8*(reg>>2)+4*(lane>>5)  [HW-verified m74/m101].
//
// 3-barrier buffer rotation (was 4): Xb is dead after P1's reads, Ybuf after
// P2's reads, so W->Xb and X'->Ybuf; X/Y buffer roles swap each iteration.
//   P1: Y = X Xt   (A,B from Xb; diag waves share frags) -> write Y to Ybuf, b1
//   P2: T = Y Y    (from Ybuf; Y symmetric), W = b*Y + c*T -> write W to Xb, b2
//   P3: V = W X    (A from Xb(W), B from bufT(Xt)), X' = a*X + V
//       -> write X' to Ybuf, b3, write X't to bufT (read next iter after b2')
// Last iteration skips all writes/b3; X' goes straight to global.
// ---------------------------------------------------------------------------
__device__ inline bf16x8 swap16(bf16x8 v) {
    union { bf16x8 v8; unsigned int u[4]; } x;
    x.v8 = v;
    #pragma unroll
    for (int i = 0; i < 4; i++) x.u[i] = (x.u[i] >> 16) | (x.u[i] << 16);
    return x.v8;
}

__device__ inline f32x16 mmQ32(const unsigned short* __restrict__ bufA,
                               const unsigned short* __restrict__ bufB,
                               int ar0, int br0, int row31, int half, bool share) {
    f32x16 acc = {0.f, 0.f, 0.f, 0.f, 0.f, 0.f, 0.f, 0.f,
                  0.f, 0.f, 0.f, 0.f, 0.f, 0.f, 0.f, 0.f};
    const unsigned short* pa = &bufA[(ar0 + row31) * IST + half * 8];
    const unsigned short* pb = &bufB[(br0 + row31) * IST + half * 8];
    bool sh = share && (ar0 == br0);
    #pragma unroll
    for (int g = 0; g < 8; g++) {
        bf16x8 a = *(const bf16x8*)&pa[g * 16];
        bf16x8 b = sh ? a : *(const bf16x8*)&pb[g * 16];
        acc = __builtin_amdgcn_mfma_f32_32x32x16_bf16(a, b, acc, 0, 0, 0);
        acc = __builtin_amdgcn_mfma_f32_32x32x16_bf16(swap16(a), b, acc, 0, 0, 0);
    }
    return acc;
}

// store quadrant row-major into interleaved buffer: 16 u32 writes
__device__ inline void writeRow32(unsigned short* buf, const f32x16& M,
                                  int ar0, int br0, int col31, int half) {
    #pragma unroll
    for (int r = 0; r < 16; r++) {
        int row = ar0 + (r & 3) + 8 * (r >> 2) + 4 * half;
        unsigned short h, l;
        split2(M[r], h, l);
        *(unsigned int*)&buf[row * IST + 2 * (br0 + col31)] = (unsigned)h | ((unsigned)l << 16);
    }
}

// store quadrant transposed: per reg-group of 4 consecutive rows -> one uint4
__device__ inline void writeCol32(unsigned short* buf, const f32x16& M,
                                  int ar0, int br0, int col31, int half) {
    #pragma unroll
    for (int G = 0; G < 4; G++) {
        unsigned int d[4];
        #pragma unroll
        for (int r = 0; r < 4; r++) {
            unsigned short h, l;
            split2(M[G * 4 + r], h, l);
            d[r] = (unsigned)h | ((unsigned)l << 16);
        }
        *(uint4*)&buf[(br0 + col31) * IST + 2 * (ar0 + 8 * G + 4 * half)] =
            make_uint4(d[0], d[1], d[2], d[3]);
    }
}

__global__ __launch_bounds__(256, 3) void polar_kernel(const float* __restrict__ chunkS,
                                                       float* __restrict__ Z) {
    __shared__ __align__(16) unsigned short bufA[64 * IST];
    __shared__ __align__(16) unsigned short bufB[64 * IST];
    __shared__ __align__(16) unsigned short bufT[64 * IST];
    __shared__ float red[4];
    int tid = threadIdx.x;
    int w = tid >> 6, lane = tid & 63;
    int half = lane >> 5, col31 = lane & 31;
    int ar0 = (w >> 1) * 32, br0 = (w & 1) * 32;
    size_t base = (size_t)blockIdx.x * 4096;

    f32x16 Xc;
    float ss = 0.f;
    #pragma unroll
    for (int r = 0; r < 16; r++) {
        int row = ar0 + (r & 3) + 8 * (r >> 2) + 4 * half;
        float v = chunkS[base + (size_t)row * 64 + br0 + col31];
        Xc[r] = v;
        ss += v * v;
    }
    ss += __shfl_xor(ss, 1);  ss += __shfl_xor(ss, 2);  ss += __shfl_xor(ss, 4);
    ss += __shfl_xor(ss, 8);  ss += __shfl_xor(ss, 16); ss += __shfl_xor(ss, 32);
    if (lane == 0) red[w] = ss;
    __syncthreads();
    float sc = 1.f / (sqrtf(red[0] + red[1] + red[2] + red[3]) + 1e-7f);
    #pragma unroll
    for (int r = 0; r < 16; r++) Xc[r] *= sc;

    unsigned short* Xb = bufA;
    unsigned short* Ybuf = bufB;
    writeRow32(Xb, Xc, ar0, br0, col31, half);
    writeCol32(bufT, Xc, ar0, br0, col31, half);
    __syncthreads();

    const float na = 3.4445f, nb = -4.7750f, ncf = 2.0315f;
    for (int it = 0; it < NS_; ++it) {
        // ---- P1: Y = X Xt ----
        f32x16 Yc = mmQ32(Xb, Xb, ar0, br0, col31, half, true);
        writeRow32(Ybuf, Yc, ar0, br0, col31, half);
        __syncthreads();                        // b1: Y ready; Xb reads done
        // ---- P2: T = Y Y ; W = b*Y + c*T -> dead Xb ----
        f32x16 Tc = mmQ32(Ybuf, Ybuf, ar0, br0, col31, half, true);
        #pragma unroll
        for (int r = 0; r < 16; r++) Tc[r] = nb * Yc[r] + ncf * Tc[r];
        writeRow32(Xb, Tc, ar0, br0, col31, half);
        __syncthreads();                        // b2: W ready; Ybuf reads done
        // ---- P3: V = W X ; X' = a*X + V ----
        f32x16 Vc = mmQ32(Xb, bufT, ar0, br0, col31, half, false);
        #pragma unroll
        for (int r = 0; r < 16; r++) Xc[r] = na * Xc[r] + Vc[r];
        if (it != NS_ - 1) {
            writeRow32(Ybuf, Xc, ar0, br0, col31, half);  // X' -> dead Ybuf
            __syncthreads();                    // b3: X' ready; bufT reads done
            writeCol32(bufT, Xc, ar0, br0, col31, half);  // next read after b2'
            unsigned short* t = Xb; Xb = Ybuf; Ybuf = t;  // rotate roles
        }
    }
    #pragma unroll
    for (int r = 0; r < 16; r++) {
        int row = ar0 + (r & 3) + 8 * (r >> 2) + 4 * half;
        Z[base + (size_t)row * 64 + br0 + col31] = Xc[r];
    }
}

// ---------------------------------------------------------------------------
// Fused: m_y(ch) + chunk_s(ch+1); Zb prefetched one step ahead (branchless
// wrapped index) and unrolled x4 so independent shuffle-reductions pipeline.
// ---------------------------------------------------------------------------
__global__ __launch_bounds__(256) void fused_my_cs(const float* __restrict__ Zb,
                                                   const float* __restrict__ qbuf,
                                                   const float* __restrict__ kbuf,
                                                   const float* __restrict__ vbuf,
                                                   const float* __restrict__ gates,
                                                   float* __restrict__ Mc,
                                                   float* __restrict__ Sc,
                                                   float* __restrict__ chunkS,
                                                   float* __restrict__ ybuf,
                                                   int chunk) {
    __shared__ float buf[CS_][68];
    __shared__ float Mrow[8][68];
    __shared__ float errS[CS_][8];
    __shared__ float alS[CS_], thS[CS_], etS[CS_], gmS[CS_];
    int tid = threadIdx.x, idx = blockIdx.x;
    int vt = idx & 7, h = (idx >> 3) & 15, b = idx >> 7;
    int c0t = chunk * CS_;
    {
        int row = tid >> 2, col = (tid & 3) * 16;
        const float* src = &qbuf[((size_t)(b * T_ + c0t + row) * H_ + h) * D_];
        #pragma unroll
        for (int i = 0; i < 4; i++)
            *(float4*)&buf[row][col + i * 4] = *(const float4*)&src[col + i * 4];
    }
    if (tid < CS_) alS[tid] = gates[0 * (B_ * T_ * H_) + (b * T_ + c0t + tid) * H_ + h];
    __syncthreads();
    int vl = tid >> 5, k0 = (tid & 31) * 2;
    size_t mIdx = ((size_t)(b * H_ + h)) * 4096 + (vt * 8 + vl) * 64 + k0;
    size_t zrow = ((size_t)(b * H_ + h) * CS_) * 4096 + (vt * 8 + vl) * 64 + k0;
    float M0 = Mc[mIdx], M1 = Mc[mIdx + 1];
    float2 z = *(const float2*)&Zb[zrow];
    #pragma unroll 4
    for (int c = 0; c < CS_; c++) {
        int cn = (c + 1) & (CS_ - 1);
        float2 znext = *(const float2*)&Zb[zrow + (size_t)cn * 4096];
        float al = alS[c];
        M0 = al * M0 + z.x;
        M1 = al * M1 + z.y;
        float2 qv = *(float2*)&buf[c][k0];
        float p = M0 * qv.x + M1 * qv.y;
        p += __shfl_xor(p, 1);  p += __shfl_xor(p, 2);  p += __shfl_xor(p, 4);
        p += __shfl_xor(p, 8);  p += __shfl_xor(p, 16);
        if ((tid & 31) == 0)
            ybuf[((size_t)(b * T_ + c0t + c) * H_ + h) * D_ + vt * 8 + vl] = p;
        z = znext;
    }
    Mc[mIdx] = M0; Mc[mIdx + 1] = M1;
    if (chunk + 1 >= NC_) return;
    int c1t = c0t + CS_;
    __syncthreads();
    Mrow[vl][k0] = M0; Mrow[vl][k0 + 1] = M1;
    {
        int row = tid >> 2, col = (tid & 3) * 16;
        const float* src = &kbuf[((size_t)(b * T_ + c1t + row) * H_ + h) * D_];
        #pragma unroll
        for (int i = 0; i < 4; i++)
            *(float4*)&buf[row][col + i * 4] = *(const float4*)&src[col + i * 4];
    }
    if (tid < CS_)           thS[tid] = gates[2 * (B_ * T_ * H_) + (b * T_ + c1t + tid) * H_ + h];
    else if (tid < 2 * CS_)  { int t = tid - CS_;     etS[t] = gates[1 * (B_ * T_ * H_) + (b * T_ + c1t + t) * H_ + h]; }
    else if (tid < 3 * CS_)  { int t = tid - 2 * CS_; gmS[t] = gates[3 * (B_ * T_ * H_) + (b * T_ + c1t + t) * H_ + h]; }
    __syncthreads();
    {
        int t = tid >> 2, v0 = (tid & 3) * 2;
        float s0 = 0.f, s1 = 0.f;
        #pragma unroll
        for (int k = 0; k < 64; k += 4) {
            float4 kv = *(float4*)&buf[t][k];
            float4 m0v = *(float4*)&Mrow[v0][k];
            float4 m1v = *(float4*)&Mrow[v0 + 1][k];
            s0 += kv.x * m0v.x + kv.y * m0v.y + kv.z * m0v.z + kv.w * m0v.w;
            s1 += kv.x * m1v.x + kv.y * m1v.y + kv.z * m1v.z + kv.w * m1v.w;
        }
        const float* vp = &vbuf[((size_t)(b * T_ + c1t + t) * H_ + h) * D_ + vt * 8 + v0];
        errS[t][v0]     = s0 - vp[0];
        errS[t][v0 + 1] = s1 - vp[1];
    }
    __syncthreads();
    float S0 = Sc[mIdx], S1 = Sc[mIdx + 1];
    float ring0[16] = {}, ring1[16] = {};
    float cum0 = 0.f, cum1 = 0.f;
    for (int cb = 0; cb < 4; ++cb) {
        #pragma unroll
        for (int ci = 0; ci < 16; ++ci) {
            int cc = cb * 16 + ci;
            float er = 2.f * errS[cc][vl];
            float2 kv = *(float2*)&buf[cc][k0];
            float g = gmS[cc];
            cum0 += g * er * kv.x;
            cum1 += g * er * kv.y;
            float uw0 = cum0 - ring0[ci];
            float uw1 = cum1 - ring1[ci];
            ring0[ci] = cum0; ring1[ci] = cum1;
            float th = thS[cc], et = etS[cc];
            S0 = th * S0 - et * uw0;
            S1 = th * S1 - et * uw1;
            size_t o = ((size_t)((b * H_ + h) * CS_ + cc)) * 4096 + (vt * 8 + vl) * 64 + k0;
            *(float2*)&chunkS[o] = make_float2(S0, S1);
        }
    }
    Sc[mIdx] = S0; Sc[mIdx + 1] = S1;
}

// ---------------------------------------------------------------------------
extern "C" void kernel_launch(void* const* d_in, const int* in_sizes, int n_in,
                              void* d_out, int out_size, void* d_ws, size_t ws_size,
                              hipStream_t stream) {
    (void)in_sizes; (void)n_in; (void)out_size; (void)ws_size;
    const float* x     = (const float*)d_in[0];
    const float* Wq    = (const float*)d_in[1];
    const float* Wk    = (const float*)d_in[2];
    const float* Wv    = (const float*)d_in[3];
    const float* Wproj = (const float*)d_in[4];
    const float* cqw   = (const float*)d_in[5];
    const float* cqb   = (const float*)d_in[6];
    const float* ckw   = (const float*)d_in[7];
    const float* ckb   = (const float*)d_in[8];
    const float* cvw   = (const float*)d_in[9];
    const float* cvb   = (const float*)d_in[10];
    const float* Wa    = (const float*)d_in[11];
    const float* We    = (const float*)d_in[12];
    const float* Wt    = (const float*)d_in[13];
    const float* Wg    = (const float*)d_in[14];

    float* ws  = (float*)d_ws;
    float* Qb  = ws;                      // 4194304 floats (B,T,C)
    float* Kb  = Qb + 4194304;
    float* Vb  = Kb + 4194304;
    float* Yb  = Vb + 4194304;
    float* Gb  = Yb + 4194304;            // 262144 (4,B,T,H)
    float* Mc  = Gb + 262144;             // 131072 (B,H,D,D)
    float* Sc  = Mc + 131072;             // 131072
    float* CSb = Sc + 131072;             // 8388608 (B,H,CS,D,D)
    float* Zb  = CSb + 8388608;           // 8388608
    unsigned short* su = (unsigned short*)CSb;
    unsigned short* xh  = su;
    unsigned short* xl  = su + 4194304;
    unsigned short* Wqh = su + 8388608,  *Wql = su + 9437184;
    unsigned short* Wkh = su + 10485760, *Wkl = su + 11534336;
    unsigned short* Wvh = su + 12582912, *Wvl = su + 13631488;
    float* bufA = Zb;

    hipMemsetAsync(Mc, 0, 2 * 131072 * sizeof(float), stream);

    split_kernel<<<4096, 256, 0, stream>>>(x, xh, xl, 4194304);
    split_kernel<<<1024, 256, 0, stream>>>(Wq, Wqh, Wql, 1048576);
    split_kernel<<<1024, 256, 0, stream>>>(Wk, Wkh, Wkl, 1048576);
    split_kernel<<<1024, 256, 0, stream>>>(Wv, Wvh, Wvl, 1048576);

    dim3 gs(C_ / 128, (B_ * T_) / 128);
    gemm_split<<<gs, 256, 0, stream>>>(xh, xl, Wqh, Wql, bufA);
    conv_kernel<<<B_ * T_, 256, 0, stream>>>(bufA, cqw, cqb, Qb, 1);
    gemm_split<<<gs, 256, 0, stream>>>(xh, xl, Wkh, Wkl, bufA);
    conv_kernel<<<B_ * T_, 256, 0, stream>>>(bufA, ckw, ckb, Kb, 2);
    gemm_split<<<gs, 256, 0, stream>>>(xh, xl, Wvh, Wvl, bufA);
    conv_kernel<<<B_ * T_, 256, 0, stream>>>(bufA, cvw, cvb, Vb, 0);
    gates_kernel<<<B_ * T_, 256, 0, stream>>>(x, Wa, We, Wt, Wg, Gb);

    chunk_s_kernel<<<B_ * H_ * 8, 256, 0, stream>>>(Kb, Vb, Gb, Mc, Sc, CSb, 0);
    for (int ch = 0; ch < NC_; ++ch) {
        polar_kernel<<<B_ * H_ * CS_, 256, 0, stream>>>(CSb, Zb);
        fused_my_cs<<<B_ * H_ * 8, 256, 0, stream>>>(Zb, Qb, Kb, Vb, Gb, Mc, Sc, CSb, Yb, ch);
    }

    unsigned short* Ybh = su, *Ybl = su + 4194304;
    unsigned short* Wph = su + 8388608, *Wpl = su + 9437184;
    split_kernel<<<4096, 256, 0, stream>>>(Yb, Ybh, Ybl, 4194304);
    split_kernel<<<1024, 256, 0, stream>>>(Wproj, Wph, Wpl, 1048576);
    gemm_split<<<gs, 256, 0, stream>>>(Ybh, Ybl, Wph, Wpl, (float*)d_out);
}